// Round 1
// 249.734 us; speedup vs baseline: 1.0244x; 1.0244x over previous
//
#include <hip/hip_runtime.h>

#define L_SEQ 512
#define BATCH 2
#define NROWS (BATCH*L_SEQ)   // 1024
#define DMODEL 512
#define DINNER 1024
#define DSTATE 128
#define NHEADSM 16
#define CONVD 1280
#define DINPROJ 2320
#define QCH 32
#define NCH 16
#define WI_PAD 2368           // 2320 padded to x64
#define WH_PAD 1024           // 1000 padded to x64

// ws float offsets (after 256B header holding the dtype flag)
#define W_CONVW 0
#define W_CONVB 10240
#define W_DTB   12800
#define W_ALOG  12832
#define W_DD    12864
#define W_RMSW  12896
#define W_LNW   14944
#define W_LNB   15968
#define W_HEADB 16992
#define O_X     18048
#define O_ZX    (O_X  + NROWS*DMODEL)
#define O_XC    (O_ZX + NROWS*DINPROJ)
#define O_DT    (O_XC + NROWS*CONVD)
#define O_Y     (O_DT + NROWS*NHEADSM)
#define O_O     (O_Y  + NROWS*DINNER)
#define O_LA    (O_O  + NROWS*DMODEL)
#define O_S     (O_LA + 16384)
#define O_UB    (O_S  + 4194304)
// ushort offsets within bf16 region:
#define U_WI   0
#define U_WO   2424832
#define U_WH   3473408
#define U_XBF  3997696
#define U_YBF  4521984

#define NSMALL 17992          // total small-param floats
#define NPREPW (2*WI_PAD + 2*DMODEL + WH_PAD)   // 6848 weight rows

typedef __attribute__((ext_vector_type(8))) short short8;
typedef __attribute__((ext_vector_type(4))) float floatx4;

__device__ __forceinline__ float b2f(unsigned short h){ return __uint_as_float(((unsigned)h)<<16); }
__device__ __forceinline__ unsigned short f2b(float x){
  unsigned u = __float_as_uint(x);
  return (unsigned short)((u + 0x7fffu + ((u>>16)&1u)) >> 16);
}
__device__ __forceinline__ float loadIn(const void* p, long i, int f){
  return f ? b2f(((const unsigned short*)p)[i]) : ((const float*)p)[i];
}

// async global->LDS direct copy, 16B per lane. LDS dest is wave-uniform base +
// lane*16 (linear); swizzled layouts are achieved by pre-swizzling the global
// source address per lane.
__device__ __forceinline__ void gload16(const void* g, void* l){
  __builtin_amdgcn_global_load_lds((const __attribute__((address_space(1))) void*)g,
                                   (__attribute__((address_space(3))) void*)l, 16, 0, 0);
}

// ---- dtype detect: low-16 of f32 words are a bf16 value iff data is packed bf16 ----
__global__ void k_detect(const unsigned* __restrict__ emb, int* __restrict__ flag){
  __shared__ int red[256];
  int t = threadIdx.x; int cnt = 0;
  for (int i = 0; i < 16; i++){
    unsigned w = emb[t*16 + i];
    unsigned e = (w >> 7) & 0xffu;
    cnt += (e >= 100 && e <= 126) ? 1 : 0;
  }
  red[t] = cnt; __syncthreads();
  if (t == 0){
    int s = 0;
    for (int i = 0; i < 256; i++) s += red[i];
    *flag = (s > 2048) ? 1 : 0;
  }
}

struct ConvArgs { const void* src[9]; int off[10]; };

// fused startup: small-param convert + weight bf16 prep + embedding
__global__ void k_prep(ConvArgs a, const void* __restrict__ wi, const void* __restrict__ wo,
                       const void* __restrict__ wh, const int* __restrict__ tok,
                       const void* __restrict__ emb, const int* __restrict__ flag,
                       float* __restrict__ dstSmall,
                       unsigned short* __restrict__ WiB, unsigned short* __restrict__ WoB,
                       unsigned short* __restrict__ WhB,
                       float* __restrict__ x, unsigned short* __restrict__ xbf)
{
  int f = *flag;
  int blk = blockIdx.x;
  if (blk < 71){
    int i = blk*256 + threadIdx.x;
    if (i < a.off[9]){
      int s = 0;
      while (i >= a.off[s+1]) s++;
      dstSmall[i] = loadIn(a.src[s], i - a.off[s], f);
    }
    return;
  }
  blk -= 71;
  if (blk < NPREPW){
    int r = blk;
    const void* src = nullptr; unsigned short* dst; long sb = 0, db; int K; bool zero = false;
    if (r < 2*WI_PAD){
      int layer = r / WI_PAD, row = r % WI_PAD;
      K = DMODEL; dst = WiB; db = ((long)layer*WI_PAD + row)*DMODEL;
      if (row < DINPROJ){ src = wi; sb = ((long)layer*DINPROJ + row)*DMODEL; } else zero = true;
    } else if (r < 2*WI_PAD + 2*DMODEL){
      int rr = r - 2*WI_PAD;
      K = DINNER; dst = WoB; db = (long)rr*DINNER;
      src = wo; sb = db;
    } else {
      int row = r - 2*WI_PAD - 2*DMODEL;
      K = DMODEL; dst = WhB; db = (long)row*DMODEL;
      if (row < 1000){ src = wh; sb = db; } else zero = true;
    }
    for (int c = threadIdx.x; c < K; c += 256)
      dst[db + c] = zero ? (unsigned short)0
                         : (f ? ((const unsigned short*)src)[sb + c] : f2b(((const float*)src)[sb + c]));
    return;
  }
  int r = blk - NPREPW;   // embed row
  long base = (long)tok[r] * DMODEL;
  for (int c = threadIdx.x; c < DMODEL; c += 256){
    float v = loadIn(emb, base + c, f);
    x[(long)r*DMODEL + c] = v;
    xbf[(long)r*DMODEL + c] = f ? ((const unsigned short*)emb)[base + c] : f2b(v);
  }
}

// ======== bf16 MFMA GEMM: C[M,N] = A[M,K] @ B[N,K]^T (+bias) ========
// Double-buffered global_load_lds 2-phase pipeline (T3-minimum):
//   STAGE(next) issued BEFORE ds_read+MFMA on current -> load latency hides
//   under compute; one vmcnt(0)+barrier per K-step.
// LDS stays linear (gload_lds requirement); the XOR-swizzle conflict-free
// read layout is obtained by pre-swizzling the per-lane GLOBAL source:
// LDS chunk (row r, pos p) holds global k-group p^(r&7).
template<int BM, int BN>
__global__ __launch_bounds__(256) void k_mfma_nt(
    const unsigned short* __restrict__ A, const unsigned short* __restrict__ B,
    void* __restrict__ C, int M, int N, int K,
    const float* __restrict__ bias, const int* __restrict__ flag, int outDual)
{
  constexpr int MI = BM/32;   // 16-row fragments per wave (m-dir)
  constexpr int NI = BN/32;
  constexpr int CA = BM/32;   // gload_lds calls per wave for A (1KB each)
  constexpr int CB = BN/32;
  __shared__ __align__(16) unsigned short As[2][BM*64];
  __shared__ __align__(16) unsigned short Bs[2][BN*64];
  int f = *flag;
  int t = threadIdx.x;
  int w = t >> 6, lane = t & 63;
  int quad = lane >> 4, l16 = lane & 15;
  int m0 = blockIdx.y * BM, n0 = blockIdx.x * BN;
  int wm = (w & 1) * (BM/2), wn = (w >> 1) * (BN/2);
  floatx4 acc[MI][NI];
  #pragma unroll
  for (int mi = 0; mi < MI; mi++)
    #pragma unroll
    for (int ni = 0; ni < NI; ni++) acc[mi][ni] = (floatx4){0.f,0.f,0.f,0.f};

  // per-lane staging addresses (chunk i -> row i>>3, LDS pos i&7, global
  // k-group (i&7)^(r&7); LDS linear by chunk, 16B per chunk)
  const char* Ag = (const char*)A;
  const char* Bg = (const char*)B;
  long aOff[CA]; int aL[CA];
  #pragma unroll
  for (int j = 0; j < CA; j++){
    int i = (w*CA + j)*64 + lane;
    int r = i >> 3, g = (i & 7) ^ (r & 7);
    aOff[j] = ((long)(m0 + r)*K + g*8)*2;
    aL[j] = (w*CA + j)*1024;
  }
  long bOff[CB]; int bL[CB];
  #pragma unroll
  for (int j = 0; j < CB; j++){
    int i = (w*CB + j)*64 + lane;
    int r = i >> 3, g = (i & 7) ^ (r & 7);
    bOff[j] = ((long)(n0 + r)*K + g*8)*2;
    bL[j] = (w*CB + j)*1024;
  }

  const int NKI = K >> 6;
  // prologue: stage k-tile 0 into buffer 0
  #pragma unroll
  for (int j = 0; j < CA; j++) gload16(Ag + aOff[j], (char*)As[0] + aL[j]);
  #pragma unroll
  for (int j = 0; j < CB; j++) gload16(Bg + bOff[j], (char*)Bs[0] + bL[j]);
  asm volatile("s_waitcnt vmcnt(0)" ::: "memory");
  __syncthreads();

  for (int ki = 0; ki < NKI; ki++){
    int cur = ki & 1;
    if (ki + 1 < NKI){          // issue next tile's loads (async, direct to LDS)
      long kb = (long)(ki + 1)*128;
      #pragma unroll
      for (int j = 0; j < CA; j++) gload16(Ag + aOff[j] + kb, (char*)As[cur^1] + aL[j]);
      #pragma unroll
      for (int j = 0; j < CB; j++) gload16(Bg + bOff[j] + kb, (char*)Bs[cur^1] + bL[j]);
    }
    const unsigned short* Ac = As[cur];
    const unsigned short* Bc = Bs[cur];
    #pragma unroll
    for (int ks = 0; ks < 2; ks++){
      short8 af[MI], bfr[NI];
      #pragma unroll
      for (int mi = 0; mi < MI; mi++){
        int r = wm + mi*16 + l16;
        int pos = ((ks << 2) + quad) ^ (r & 7);
        af[mi] = *(const short8*)&Ac[r*64 + pos*8];
      }
      #pragma unroll
      for (int ni = 0; ni < NI; ni++){
        int r = wn + ni*16 + l16;
        int pos = ((ks << 2) + quad) ^ (r & 7);
        bfr[ni] = *(const short8*)&Bc[r*64 + pos*8];
      }
      #pragma unroll
      for (int mi = 0; mi < MI; mi++)
        #pragma unroll
        for (int ni = 0; ni < NI; ni++)
          acc[mi][ni] = __builtin_amdgcn_mfma_f32_16x16x32_bf16(af[mi], bfr[ni], acc[mi][ni], 0, 0, 0);
    }
    // drain this wave's async loads, then barrier: next iter overwrites the
    // buffer all waves just finished reading.
    asm volatile("s_waitcnt vmcnt(0)" ::: "memory");
    __syncthreads();
  }
  #pragma unroll
  for (int mi = 0; mi < MI; mi++)
    #pragma unroll
    for (int ni = 0; ni < NI; ni++){
      int col = n0 + wn + ni*16 + l16;
      if (col >= N) continue;
      float bv = bias ? bias[col] : 0.f;
      #pragma unroll
      for (int rr = 0; rr < 4; rr++){
        int row = m0 + wm + mi*16 + (quad << 2) + rr;
        float v = acc[mi][ni][rr] + bv;
        long idx = (long)row*N + col;
        if (outDual && f) ((unsigned short*)C)[idx] = f2b(v);
        else              ((float*)C)[idx] = v;
      }
    }
}

__global__ __launch_bounds__(256) void k_conv_dt(
    const float* __restrict__ zx, const float* __restrict__ cw, const float* __restrict__ cb,
    const float* __restrict__ dtb, float* __restrict__ xc, float* __restrict__ dt)
{
  int r = blockIdx.x; int b = r >> 9, l = r & 511;
  int t = threadIdx.x;
  for (int c = t; c < CONVD; c += 256){
    float s = cb[c];
    #pragma unroll
    for (int k = 0; k < 4; k++){
      int pos = l - 3 + k;
      if (pos >= 0)
        s = fmaf(zx[(long)(b*L_SEQ + pos)*DINPROJ + DINNER + c], cw[c*4 + k], s);
    }
    xc[(long)r*CONVD + c] = s / (1.f + __expf(-s));   // silu
  }
  if (t < NHEADSM){
    float v = zx[(long)r*DINPROJ + DINNER + CONVD + t] + dtb[t];
    dt[r*NHEADSM + t] = (v > 20.f) ? v : log1pf(__expf(v));  // softplus
  }
}

// ================= chunked SSD scan (MFMA) =================
// chunk1 per (c,h,b): S = (coef.X)^T B  [64x128,K=32], G = C.B^T [32x32,K=128],
// Y = G.X + D*x [32x64,K=32]. All via NT mfma primitive (both operands [out][K]).
__global__ __launch_bounds__(256) void k_chunk1(
    const float* __restrict__ xc, const float* __restrict__ dtbuf,
    const float* __restrict__ alog, const float* __restrict__ dvec,
    float* __restrict__ S, float* __restrict__ LAb, float* __restrict__ y)
{
  int c = blockIdx.x, h = blockIdx.y, b = blockIdx.z;
  int t = threadIdx.x, w = t >> 6, lane = t & 63;
  int quad = lane >> 4, l16 = lane & 15;
  int l0 = c*QCH;
  __shared__ unsigned short XT[64*40];    // XT[p][j] = X[j][p]
  __shared__ unsigned short BTc[128*40];  // BTc[n][j] = coef[j]*B[j][n]
  __shared__ unsigned short Bb[32*136];   // B[j][n]
  __shared__ unsigned short Cb[32*136];   // C[i][n]
  __shared__ unsigned short Gb[32*40];    // G[i][j]
  __shared__ float dtl[32], lal[32], coef[32];
  float A  = -__expf(alog[h]);
  float Dv = dvec[h];

  // prefetch globals into regs (overlaps with dt prefix scan)
  float xv[8];
  #pragma unroll
  for (int k = 0; k < 8; k++){
    int idx = t + k*256; int j = idx >> 6, p = idx & 63;
    xv[k] = xc[(long)(b*L_SEQ + l0 + j)*CONVD + h*64 + p];
  }
  float bv[16], cv[16];
  #pragma unroll
  for (int k = 0; k < 16; k++){
    int idx = t + k*256; int j = idx >> 7, n = idx & 127;
    long rb = (long)(b*L_SEQ + l0 + j)*CONVD + DINNER;
    bv[k] = xc[rb + n];
    cv[k] = xc[rb + DSTATE + n];
  }
  // lane-parallel inclusive prefix over dt (replaces serial t==0 chain + 2 barriers)
  if (t < 32){
    float d = dtbuf[(b*L_SEQ + l0 + t)*NHEADSM + h];
    dtl[t] = d;
    float s = d;
    #pragma unroll
    for (int o = 1; o < 32; o <<= 1){
      float u = __shfl_up(s, o, 32);
      if (t >= o) s += u;
    }
    float la = s * A;
    lal[t] = la;
    float tot = __shfl(s, 31, 32) * A;
    coef[t] = __expf(tot - la) * d;
    LAb[(b*NHEADSM + h)*L_SEQ + l0 + t] = la;
  }
  __syncthreads();
  #pragma unroll
  for (int k = 0; k < 8; k++){
    int idx = t + k*256; int j = idx >> 6, p = idx & 63;
    XT[p*40 + j] = f2b(xv[k]);
  }
  #pragma unroll
  for (int k = 0; k < 16; k++){
    int idx = t + k*256; int j = idx >> 7, n = idx & 127;
    Bb[j*136 + n] = f2b(bv[k]);
    Cb[j*136 + n] = f2b(cv[k]);
    BTc[n*40 + j] = f2b(bv[k] * coef[j]);
  }
  __syncthreads();

  // ---- S: wave w owns p-block w; 8 n-blocks ----
  short8 afS = *(const short8*)&XT[(w*16 + l16)*40 + quad*8];
  floatx4 accS[8];
  #pragma unroll
  for (int nb = 0; nb < 8; nb++){
    short8 bfS = *(const short8*)&BTc[(nb*16 + l16)*40 + quad*8];
    accS[nb] = __builtin_amdgcn_mfma_f32_16x16x32_bf16(afS, bfS, (floatx4){0.f,0.f,0.f,0.f}, 0, 0, 0);
  }
  // ---- G: wave w -> (ti = w&1, tj = w>>1) ----
  int ti = w & 1, tj = w >> 1;
  floatx4 accG = (floatx4){0.f,0.f,0.f,0.f};
  #pragma unroll
  for (int ks = 0; ks < 4; ks++){
    short8 ga = *(const short8*)&Cb[(ti*16 + l16)*136 + ks*32 + quad*8];
    short8 gb = *(const short8*)&Bb[(tj*16 + l16)*136 + ks*32 + quad*8];
    accG = __builtin_amdgcn_mfma_f32_16x16x32_bf16(ga, gb, accG, 0, 0, 0);
  }
  // store S (C-layout: row=quad*4+rr, col=l16)
  long sb = ((long)((b*NHEADSM + h)*NCH + c))*8192;
  #pragma unroll
  for (int nb = 0; nb < 8; nb++)
    #pragma unroll
    for (int rr = 0; rr < 4; rr++)
      S[sb + (w*16 + quad*4 + rr)*128 + nb*16 + l16] = accS[nb][rr];
  // mask/exp G, write bf16
  #pragma unroll
  for (int rr = 0; rr < 4; rr++){
    int i = ti*16 + quad*4 + rr, j = tj*16 + l16;
    float g = (j <= i) ? __expf(lal[i] - lal[j]) * dtl[j] * accG[rr] : 0.f;
    Gb[i*40 + j] = f2b(g);
  }
  __syncthreads();
  // ---- Y: wave w -> (ti = w&1, pb = (w>>1)*2 + s) ----
  short8 ag = *(const short8*)&Gb[(ti*16 + l16)*40 + quad*8];
  #pragma unroll
  for (int s = 0; s < 2; s++){
    int pb = (w >> 1)*2 + s;
    short8 bx = *(const short8*)&XT[(pb*16 + l16)*40 + quad*8];
    floatx4 accY = __builtin_amdgcn_mfma_f32_16x16x32_bf16(ag, bx, (floatx4){0.f,0.f,0.f,0.f}, 0, 0, 0);
    #pragma unroll
    for (int rr = 0; rr < 4; rr++){
      int i = ti*16 + quad*4 + rr, p = pb*16 + l16;
      float xval = b2f(XT[p*40 + i]);
      y[(long)(b*L_SEQ + l0 + i)*DINNER + h*64 + p] = fmaf(Dv, xval, accY[rr]);
    }
  }
}

// chunk2: state propagation, IN-PLACE, one thread per state element.
__global__ __launch_bounds__(256) void k_chunk2(
    float* __restrict__ S, const float* __restrict__ LAb)
{
  int bh = blockIdx.x >> 5;
  int e = ((blockIdx.x & 31) << 8) + threadIdx.x;
  long base = (long)bh*NCH*8192 + e;
  int laBase = bh*L_SEQ;
  float lam[NCH];
  #pragma unroll
  for (int c = 0; c < NCH; c++) lam[c] = __expf(LAb[laBase + c*QCH + QCH - 1]);
  float hr = 0.f;
  #pragma unroll
  for (int c = 0; c < NCH; c++){
    long off = base + (long)c*8192;
    float sv = S[off];
    S[off] = hr;
    hr = fmaf(hr, lam[c], sv);
  }
}

// chunk3: Y += exp(la_i) * C.H^T  [32x64, K=128] via MFMA; H double-bf16.
__global__ __launch_bounds__(256) void k_chunk3(
    const float* __restrict__ xc, const float* __restrict__ H,
    const float* __restrict__ LAb, float* __restrict__ y)
{
  int c = blockIdx.x, h = blockIdx.y, b = blockIdx.z;
  int t = threadIdx.x, w = t >> 6, lane = t & 63;
  int quad = lane >> 4, l16 = lane & 15;
  int l0 = c*QCH;
  __shared__ unsigned short Cb[32*136];
  __shared__ unsigned short Hhi[64*136];
  __shared__ unsigned short Hlo[64*136];
  __shared__ float el[32];
  if (t < 32) el[t] = __expf(LAb[(b*NHEADSM + h)*L_SEQ + l0 + t]);
  #pragma unroll
  for (int k = 0; k < 16; k++){
    int idx = t + k*256; int j = idx >> 7, n = idx & 127;
    Cb[j*136 + n] = f2b(xc[(long)(b*L_SEQ + l0 + j)*CONVD + DINNER + DSTATE + n]);
  }
  long hb = ((long)((b*NHEADSM + h)*NCH + c))*8192;
  #pragma unroll
  for (int k = 0; k < 32; k++){
    int idx = t + k*256; int p = idx >> 7, n = idx & 127;
    float v = H[hb + idx];
    unsigned short hi = f2b(v);
    Hhi[p*136 + n] = hi;
    Hlo[p*136 + n] = f2b(v - b2f(hi));
  }
  __syncthreads();
  int ti = w & 1;
  #pragma unroll
  for (int s = 0; s < 2; s++){
    int pb = (w >> 1)*2 + s;
    floatx4 acc = (floatx4){0.f,0.f,0.f,0.f};
    #pragma unroll
    for (int ks = 0; ks < 4; ks++){
      short8 a  = *(const short8*)&Cb [(ti*16 + l16)*136 + ks*32 + quad*8];
      short8 bl = *(const short8*)&Hlo[(pb*16 + l16)*136 + ks*32 + quad*8];
      short8 bh = *(const short8*)&Hhi[(pb*16 + l16)*136 + ks*32 + quad*8];
      acc = __builtin_amdgcn_mfma_f32_16x16x32_bf16(a, bl, acc, 0, 0, 0);
      acc = __builtin_amdgcn_mfma_f32_16x16x32_bf16(a, bh, acc, 0, 0, 0);
    }
    #pragma unroll
    for (int rr = 0; rr < 4; rr++){
      int i = ti*16 + quad*4 + rr, p = pb*16 + l16;
      long yb = (long)(b*L_SEQ + l0 + i)*DINNER + h*64 + p;
      y[yb] = fmaf(el[i], acc[rr], y[yb]);
    }
  }
}

__global__ __launch_bounds__(256) void k_gated_rms(
    const float* __restrict__ y, const float* __restrict__ zx, const float* __restrict__ rw,
    unsigned short* __restrict__ ybf)
{
  int r = blockIdx.x, t = threadIdx.x;
  float g[4]; float ss = 0.f;
  #pragma unroll
  for (int i = 0; i < 4; i++){
    int c = t + i*256;
    float z  = zx[(long)r*DINPROJ + c];
    float yv = y[(long)r*DINNER + c];
    float gz = z / (1.f + __expf(-z));
    g[i] = yv * gz;
    ss = fmaf(g[i], g[i], ss);
  }
  #pragma unroll
  for (int o = 1; o < 64; o <<= 1) ss += __shfl_xor(ss, o);
  __shared__ float red[4];
  int w = t >> 6, lane = t & 63;
  if (lane == 0) red[w] = ss;
  __syncthreads();
  float tot = red[0] + red[1] + red[2] + red[3];
  float sc = rsqrtf(tot / (float)DINNER + 1e-5f);
  #pragma unroll
  for (int i = 0; i < 4; i++){
    int c = t + i*256;
    ybf[(long)r*DINNER + c] = f2b(g[i] * sc * rw[c]);
  }
}

__global__ __launch_bounds__(256) void k_add_ln(
    float* __restrict__ x, const float* __restrict__ o,
    const float* __restrict__ lw, const float* __restrict__ lb,
    unsigned short* __restrict__ xbf)
{
  int r = blockIdx.x, t = threadIdx.x;
  float v[2]; float sm = 0.f;
  #pragma unroll
  for (int i = 0; i < 2; i++){ int c = t + i*256; v[i] = x[(long)r*DMODEL + c] + o[(long)r*DMODEL + c]; sm += v[i]; }
  #pragma unroll
  for (int off = 1; off < 64; off <<= 1) sm += __shfl_xor(sm, off);
  __shared__ float red[4]; __shared__ float red2[4];
  int w = t >> 6, lane = t & 63;
  if (lane == 0) red[w] = sm;
  __syncthreads();
  float mu = (red[0] + red[1] + red[2] + red[3]) / (float)DMODEL;
  float var = 0.f;
  #pragma unroll
  for (int i = 0; i < 2; i++){ v[i] -= mu; var = fmaf(v[i], v[i], var); }
  #pragma unroll
  for (int off = 1; off < 64; off <<= 1) var += __shfl_xor(var, off);
  if (lane == 0) red2[w] = var;
  __syncthreads();
  float vv = (red2[0] + red2[1] + red2[2] + red2[3]) / (float)DMODEL;
  float sc = rsqrtf(vv + 1e-5f);
  #pragma unroll
  for (int i = 0; i < 2; i++){
    int c = t + i*256;
    float ov = v[i]*sc*lw[c] + lb[c];
    x[(long)r*DMODEL + c] = ov;
    xbf[(long)r*DMODEL + c] = f2b(ov);
  }
}

extern "C" void kernel_launch(void* const* d_in, const int* in_sizes, int n_in,
                              void* d_out, int out_size, void* d_ws, size_t ws_size,
                              hipStream_t stream)
{
  const int* tokens = (const int*)d_in[0];
  const void* emb = d_in[1];
  int* flag = (int*)d_ws;
  float* ws = (float*)((char*)d_ws + 256);

  k_detect<<<1, 256, 0, stream>>>((const unsigned*)emb, flag);

  ConvArgs ca;
  const int sizes[9] = {10240, 2560, 32, 32, 32, 2048, 1024, 1024, 1000};
  const int idxs[9]  = {3, 4, 5, 6, 7, 8, 10, 11, 13};
  int off = 0;
  for (int s = 0; s < 9; s++){ ca.src[s] = d_in[idxs[s]]; ca.off[s] = off; off += sizes[s]; }
  ca.off[9] = off;

  float* X  = ws + O_X;
  float* ZX = ws + O_ZX;
  float* XC = ws + O_XC;
  float* DT = ws + O_DT;
  float* Y  = ws + O_Y;
  float* Ob = ws + O_O;
  float* LA = ws + O_LA;
  float* Sb = ws + O_S;
  unsigned short* ub  = (unsigned short*)(ws + O_UB);
  unsigned short* WiB = ub + U_WI;
  unsigned short* WoB = ub + U_WO;
  unsigned short* WhB = ub + U_WH;
  unsigned short* Xbf = ub + U_XBF;
  unsigned short* Ybf = ub + U_YBF;

  k_prep<<<71 + NPREPW + NROWS, 256, 0, stream>>>(
      ca, d_in[2], d_in[9], d_in[12], tokens, emb, flag,
      ws, WiB, WoB, WhB, X, Xbf);

  for (int layer = 0; layer < 2; layer++){
    k_mfma_nt<64,64><<<dim3(WI_PAD/64, NROWS/64), 256, 0, stream>>>(
        Xbf, WiB + (long)layer*WI_PAD*DMODEL, (void*)ZX,
        NROWS, DINPROJ, DMODEL, (const float*)nullptr, flag, 0);
    k_conv_dt<<<NROWS, 256, 0, stream>>>(
        ZX, ws + W_CONVW + layer*5120, ws + W_CONVB + layer*1280, ws + W_DTB + layer*16, XC, DT);
    k_chunk1<<<dim3(NCH, NHEADSM, BATCH), 256, 0, stream>>>(
        XC, DT, ws + W_ALOG + layer*16, ws + W_DD + layer*16, Sb, LA, Y);
    k_chunk2<<<1024, 256, 0, stream>>>(Sb, LA);
    k_chunk3<<<dim3(NCH, NHEADSM, BATCH), 256, 0, stream>>>(XC, Sb, LA, Y);
    k_gated_rms<<<NROWS, 256, 0, stream>>>(Y, ZX, ws + W_RMSW + layer*1024, Ybf);
    // out_proj: 32x32 tile -> 16x32 = 512 blocks (was 128: half the chip idle)
    k_mfma_nt<32,32><<<dim3(DMODEL/32, NROWS/32), 256, 0, stream>>>(
        Ybf, WoB + (long)layer*DMODEL*DINNER, (void*)Ob,
        NROWS, DMODEL, DINNER, (const float*)nullptr, flag, 0);
    k_add_ln<<<NROWS, 256, 0, stream>>>(X, Ob, ws + W_LNW + layer*512, ws + W_LNB + layer*512, Xbf);
  }

  // head: 32x64 tile -> 16x32 = 512 blocks (2/CU for latency hiding)
  k_mfma_nt<32,64><<<dim3(WH_PAD/64, NROWS/32), 256, 0, stream>>>(
      Xbf, WhB, d_out, NROWS, 1000, DMODEL, ws + W_HEADB, flag, 1);
}